// Round 1
// baseline (777.199 us; speedup 1.0000x reference)
//
#include <hip/hip_runtime.h>

#define BB 32
#define NN 128   // N1 = N2
#define MM 512   // M1 = M2
#define NITER 15
#define EPS2 1e-12f   // (1e-6)^2

using f4 = float4;

__device__ __forceinline__ f4 ld4(const float* p){ return *reinterpret_cast<const f4*>(p); }
__device__ __forceinline__ void st4(float* p, f4 v){ *reinterpret_cast<f4*>(p) = v; }

// ---------------- init: v = 1, flag = 1 ----------------
__global__ __launch_bounds__(256) void k_init(float* __restrict__ v, int* __restrict__ flag){
  int i = blockIdx.x * 256 + threadIdx.x;
  if (i < BB*NN*NN) v[i] = 1.0f;
  if (i == 0) *flag = 1;
}

// ---------------- K1: x1[f][b][m][p] = sum_n Q1[b][n][m] * v[b][n][p] ----------------
// Q1 = (f==0 ? H1 : G1).  out 512x128, K=128.  grid(8,2,64)
__global__ __launch_bounds__(256) void k_x1(const float* __restrict__ H1,
                                            const float* __restrict__ G1,
                                            const float* __restrict__ v,
                                            float* __restrict__ x1,
                                            const int* __restrict__ flag){
  if (*flag == 0) return;
  const int bz = blockIdx.z;
  const int f = bz >> 5, b = bz & 31;
  const float* __restrict__ Q1 = f ? G1 : H1;
  const int mT = blockIdx.x * 64;
  const int pT = blockIdx.y * 64;
  const int tid = threadIdx.x;
  const int tx = tid & 15, ty = tid >> 4;
  const int lk = tid >> 4, lc = (tid & 15) * 4;

  __shared__ float As[16][68];
  __shared__ float Bs[16][68];
  float acc[4][4] = {};

  const float* Qb = Q1 + (size_t)b * NN * MM;  // [128][512]
  const float* vb = v  + (size_t)b * NN * NN;  // [128][128]

  for (int kt = 0; kt < NN; kt += 16) {
    f4 a  = ld4(Qb + (size_t)(kt + lk) * MM + mT + lc);
    f4 bv = ld4(vb + (size_t)(kt + lk) * NN + pT + lc);
    st4(&As[lk][lc], a);
    st4(&Bs[lk][lc], bv);
    __syncthreads();
    #pragma unroll
    for (int k = 0; k < 16; ++k) {
      f4 av = ld4(&As[k][ty*4]);
      f4 bw = ld4(&Bs[k][tx*4]);
      float ar[4] = {av.x, av.y, av.z, av.w};
      float br[4] = {bw.x, bw.y, bw.z, bw.w};
      #pragma unroll
      for (int i2 = 0; i2 < 4; ++i2)
        #pragma unroll
        for (int j = 0; j < 4; ++j)
          acc[i2][j] += ar[i2] * br[j];
    }
    __syncthreads();
  }
  float* xb = x1 + ((size_t)f*BB + b) * MM * NN;
  #pragma unroll
  for (int i2 = 0; i2 < 4; ++i2){
    int m = mT + ty*4 + i2;
    st4(xb + (size_t)m * NN + pT + tx*4,
        make_float4(acc[i2][0], acc[i2][1], acc[i2][2], acc[i2][3]));
  }
}

// ---------------- K2: y[b][m][q] = Mq[b][m][q] * sum_p x1f[b][m][p]*Q2[b][p][q] ----------------
// out 512x512, K=128. grid(8,8,32), per flavor
__global__ __launch_bounds__(256) void k_y(const float* __restrict__ x1f,
                                           const float* __restrict__ Q2,
                                           const float* __restrict__ Mq,
                                           float* __restrict__ y,
                                           const int* __restrict__ flag){
  if (*flag == 0) return;
  const int b = blockIdx.z;
  const int mT = blockIdx.x * 64;
  const int qT = blockIdx.y * 64;
  const int tid = threadIdx.x;
  const int tx = tid & 15, ty = tid >> 4;
  const int amm = tid >> 2, ak4 = (tid & 3) * 4;   // transposed A load
  const int lk = tid >> 4, lc = (tid & 15) * 4;    // direct B load

  __shared__ float As[16][68];
  __shared__ float Bs[16][68];
  float acc[4][4] = {};

  const float* xb = x1f + (size_t)b * MM * NN;  // [512][128]
  const float* Qb = Q2  + (size_t)b * NN * MM;  // [128][512]

  for (int kt = 0; kt < NN; kt += 16) {
    f4 a = ld4(xb + (size_t)(mT + amm) * NN + kt + ak4);
    As[ak4+0][amm] = a.x; As[ak4+1][amm] = a.y; As[ak4+2][amm] = a.z; As[ak4+3][amm] = a.w;
    f4 bv = ld4(Qb + (size_t)(kt + lk) * MM + qT + lc);
    st4(&Bs[lk][lc], bv);
    __syncthreads();
    #pragma unroll
    for (int k = 0; k < 16; ++k) {
      f4 av = ld4(&As[k][ty*4]);
      f4 bw = ld4(&Bs[k][tx*4]);
      float ar[4] = {av.x, av.y, av.z, av.w};
      float br[4] = {bw.x, bw.y, bw.z, bw.w};
      #pragma unroll
      for (int i2 = 0; i2 < 4; ++i2)
        #pragma unroll
        for (int j = 0; j < 4; ++j)
          acc[i2][j] += ar[i2] * br[j];
    }
    __syncthreads();
  }
  const float* Mb = Mq + (size_t)b * MM * MM;
  float* yb = y + (size_t)b * MM * MM;
  #pragma unroll
  for (int i2 = 0; i2 < 4; ++i2){
    int m = mT + ty*4 + i2;
    f4 mq = ld4(Mb + (size_t)m * MM + qT + tx*4);
    st4(yb + (size_t)m * MM + qT + tx*4,
        make_float4(acc[i2][0]*mq.x, acc[i2][1]*mq.y, acc[i2][2]*mq.z, acc[i2][3]*mq.w));
  }
}

// ---------------- K3: z1[b][n][q] = sum_m P1[b][n][m]*y[b][m][q] ----------------
// out 128x512, K=512. grid(2,8,32), per flavor
__global__ __launch_bounds__(256) void k_z1(const float* __restrict__ P1,
                                            const float* __restrict__ y,
                                            float* __restrict__ z1,
                                            const int* __restrict__ flag){
  if (*flag == 0) return;
  const int b = blockIdx.z;
  const int nT = blockIdx.x * 64;
  const int qT = blockIdx.y * 64;
  const int tid = threadIdx.x;
  const int tx = tid & 15, ty = tid >> 4;
  const int amm = tid >> 2, ak4 = (tid & 3) * 4;
  const int lk = tid >> 4, lc = (tid & 15) * 4;

  __shared__ float As[16][68];
  __shared__ float Bs[16][68];
  float acc[4][4] = {};

  const float* Pb = P1 + (size_t)b * NN * MM;  // [128][512]
  const float* yb = y  + (size_t)b * MM * MM;  // [512][512]

  for (int kt = 0; kt < MM; kt += 16) {
    f4 a = ld4(Pb + (size_t)(nT + amm) * MM + kt + ak4);
    As[ak4+0][amm] = a.x; As[ak4+1][amm] = a.y; As[ak4+2][amm] = a.z; As[ak4+3][amm] = a.w;
    f4 bv = ld4(yb + (size_t)(kt + lk) * MM + qT + lc);
    st4(&Bs[lk][lc], bv);
    __syncthreads();
    #pragma unroll
    for (int k = 0; k < 16; ++k) {
      f4 av = ld4(&As[k][ty*4]);
      f4 bw = ld4(&Bs[k][tx*4]);
      float ar[4] = {av.x, av.y, av.z, av.w};
      float br[4] = {bw.x, bw.y, bw.z, bw.w};
      #pragma unroll
      for (int i2 = 0; i2 < 4; ++i2)
        #pragma unroll
        for (int j = 0; j < 4; ++j)
          acc[i2][j] += ar[i2] * br[j];
    }
    __syncthreads();
  }
  float* zb = z1 + (size_t)b * NN * MM;
  #pragma unroll
  for (int i2 = 0; i2 < 4; ++i2){
    int n = nT + ty*4 + i2;
    st4(zb + (size_t)n * MM + qT + tx*4,
        make_float4(acc[i2][0], acc[i2][1], acc[i2][2], acc[i2][3]));
  }
}

// ---------------- K4: z2p[b][c][n][p] = sum_{q in chunk c} z1[b][n][q]*P2[b][p][q] ----------------
// out 128x128 per (b,c), K=128 per chunk, 4 chunks. grid(2,2,128), per flavor
__global__ __launch_bounds__(256) void k_z2(const float* __restrict__ z1,
                                            const float* __restrict__ P2,
                                            float* __restrict__ z2pf,
                                            const int* __restrict__ flag){
  if (*flag == 0) return;
  const int bz = blockIdx.z;
  const int b = bz >> 2, c = bz & 3;
  const int nT = blockIdx.x * 64;
  const int pT = blockIdx.y * 64;
  const int tid = threadIdx.x;
  const int tx = tid & 15, ty = tid >> 4;
  const int amm = tid >> 2, ak4 = (tid & 3) * 4;

  __shared__ float As[16][68];
  __shared__ float Bs[16][68];
  float acc[4][4] = {};

  const float* zb = z1 + (size_t)b * NN * MM;  // [128][512]
  const float* Pb = P2 + (size_t)b * NN * MM;  // [128][512]
  const int k0 = c * 128;

  for (int kt = 0; kt < 128; kt += 16) {
    f4 a = ld4(zb + (size_t)(nT + amm) * MM + k0 + kt + ak4);
    As[ak4+0][amm] = a.x; As[ak4+1][amm] = a.y; As[ak4+2][amm] = a.z; As[ak4+3][amm] = a.w;
    f4 bv = ld4(Pb + (size_t)(pT + amm) * MM + k0 + kt + ak4);
    Bs[ak4+0][amm] = bv.x; Bs[ak4+1][amm] = bv.y; Bs[ak4+2][amm] = bv.z; Bs[ak4+3][amm] = bv.w;
    __syncthreads();
    #pragma unroll
    for (int k = 0; k < 16; ++k) {
      f4 av = ld4(&As[k][ty*4]);
      f4 bw = ld4(&Bs[k][tx*4]);
      float ar[4] = {av.x, av.y, av.z, av.w};
      float br[4] = {bw.x, bw.y, bw.z, bw.w};
      #pragma unroll
      for (int i2 = 0; i2 < 4; ++i2)
        #pragma unroll
        for (int j = 0; j < 4; ++j)
          acc[i2][j] += ar[i2] * br[j];
    }
    __syncthreads();
  }
  float* ob = z2pf + ((size_t)b * 4 + c) * NN * NN;
  #pragma unroll
  for (int i2 = 0; i2 < 4; ++i2){
    int n = nT + ty*4 + i2;
    st4(ob + (size_t)n * NN + pT + tx*4,
        make_float4(acc[i2][0], acc[i2][1], acc[i2][2], acc[i2][3]));
  }
}

// ---------------- K5: t = 0.5*(sum z2p[f][b][c]) + Mp.*v ; partial sum t^2 ----------------
// grid(8, 32)
__global__ __launch_bounds__(256) void k_comb(const float* __restrict__ z2p,
                                              const float* __restrict__ Mp,
                                              const float* __restrict__ v,
                                              float* __restrict__ t,
                                              float* __restrict__ part_nrm,
                                              const int* __restrict__ flag){
  if (*flag == 0) return;
  const int seg = blockIdx.x, b = blockIdx.y;
  const int tid = threadIdx.x;
  const float* zb0 = z2p + ((size_t)0*BB + b) * 4 * NN * NN;
  const float* zb1 = z2p + ((size_t)1*BB + b) * 4 * NN * NN;
  const size_t base = (size_t)b * NN * NN;
  float lsum = 0.f;
  #pragma unroll
  for (int i = 0; i < 8; ++i) {
    int e = seg*2048 + tid + i*256;
    float z = 0.f;
    #pragma unroll
    for (int c = 0; c < 4; ++c) z += zb0[c*NN*NN + e] + zb1[c*NN*NN + e];
    float tv = 0.5f*z + Mp[base + e] * v[base + e];
    t[base + e] = tv;
    lsum += tv * tv;
  }
  __shared__ float red[256];
  red[tid] = lsum; __syncthreads();
  for (int s = 128; s > 0; s >>= 1){ if (tid < s) red[tid] += red[tid+s]; __syncthreads(); }
  if (tid == 0) part_nrm[b*8 + seg] = red[0];
}

// ---------------- K6: u = t/nrm (div_no_nan); partial sum (u-v)^2; v = u ----------------
// grid(8, 32)
__global__ __launch_bounds__(256) void k_norm(const float* __restrict__ t,
                                              const float* __restrict__ part_nrm,
                                              float* __restrict__ v,
                                              float* __restrict__ part_diff,
                                              const int* __restrict__ flag){
  if (*flag == 0) return;
  const int seg = blockIdx.x, b = blockIdx.y;
  const int tid = threadIdx.x;
  float n2 = 0.f;
  #pragma unroll
  for (int j = 0; j < 8; ++j) n2 += part_nrm[b*8 + j];
  float nrm = sqrtf(n2);
  float rn = (nrm == 0.f) ? 0.f : 1.0f / nrm;
  const size_t base = (size_t)b * NN * NN;
  float lsum = 0.f;
  #pragma unroll
  for (int i = 0; i < 8; ++i) {
    int e = seg*2048 + tid + i*256;
    float u = t[base + e] * rn;
    float d = u - v[base + e];
    lsum += d * d;
    v[base + e] = u;
  }
  __shared__ float red[256];
  red[tid] = lsum; __syncthreads();
  for (int s = 128; s > 0; s >>= 1){ if (tid < s) red[tid] += red[tid+s]; __syncthreads(); }
  if (tid == 0) part_diff[b*8 + seg] = red[0];
}

// ---------------- K7: flag &= any_b( sum_j part_diff[b][j] >= eps^2 ) ----------------
__global__ __launch_bounds__(64) void k_flag(const float* __restrict__ part_diff,
                                             int* __restrict__ flag){
  if (*flag == 0) return;
  float s = 0.f;
  if (threadIdx.x < BB) {
    #pragma unroll
    for (int j = 0; j < 8; ++j) s += part_diff[threadIdx.x*8 + j];
  }
  unsigned long long m = __ballot(s >= EPS2);
  if (threadIdx.x == 0 && m == 0ULL) *flag = 0;
}

extern "C" void kernel_launch(void* const* d_in, const int* in_sizes, int n_in,
                              void* d_out, int out_size, void* d_ws, size_t ws_size,
                              hipStream_t stream) {
  const float* Mp = (const float*)d_in[0];
  const float* Mq = (const float*)d_in[1];
  const float* G1 = (const float*)d_in[2];
  const float* G2 = (const float*)d_in[3];
  const float* H1 = (const float*)d_in[4];
  const float* H2 = (const float*)d_in[5];
  float* v = (float*)d_out;

  float* ws = (float*)d_ws;
  size_t off = 0;
  float* x1  = ws + off; off += (size_t)2*BB*MM*NN;      // 4,194,304
  float* y   = ws + off; off += (size_t)BB*MM*MM;        // 8,388,608
  float* z1  = ws + off; off += (size_t)BB*NN*MM;        // 2,097,152
  float* z2p = ws + off; off += (size_t)2*BB*4*NN*NN;    // 4,194,304
  float* t   = ws + off; off += (size_t)BB*NN*NN;        //   524,288
  float* pn  = ws + off; off += BB*8;
  float* pd  = ws + off; off += BB*8;
  int*  flag = (int*)(ws + off);

  k_init<<<dim3((BB*NN*NN + 255)/256), 256, 0, stream>>>(v, flag);

  for (int it = 0; it < NITER; ++it) {
    k_x1<<<dim3(8, 2, 2*BB), 256, 0, stream>>>(H1, G1, v, x1, flag);
    for (int f = 0; f < 2; ++f) {
      const float* Q2 = f ? G2 : H2;
      const float* P1 = f ? H1 : G1;
      const float* P2 = f ? H2 : G2;
      const float* x1f = x1 + (size_t)f * BB * MM * NN;
      float* z2pf = z2p + (size_t)f * BB * 4 * NN * NN;
      k_y <<<dim3(8, 8, BB), 256, 0, stream>>>(x1f, Q2, Mq, y, flag);
      k_z1<<<dim3(2, 8, BB), 256, 0, stream>>>(P1, y, z1, flag);
      k_z2<<<dim3(2, 2, BB*4), 256, 0, stream>>>(z1, P2, z2pf, flag);
    }
    k_comb<<<dim3(8, BB), 256, 0, stream>>>(z2p, Mp, v, t, pn, flag);
    k_norm<<<dim3(8, BB), 256, 0, stream>>>(t, pn, v, pd, flag);
    k_flag<<<1, 64, 0, stream>>>(pd, flag);
  }
}

// Round 2
// 658.869 us; speedup vs baseline: 1.1796x; 1.1796x over previous
//
#include <hip/hip_runtime.h>

#define BB 32
#define NN 128   // N1 = N2
#define MM 512   // M1 = M2
#define NITER 15
#define EPS2 1e-12f   // (1e-6)^2

using f4 = float4;

__device__ __forceinline__ f4 ld4(const float* p){ return *reinterpret_cast<const f4*>(p); }
__device__ __forceinline__ void st4(float* p, f4 v){ *reinterpret_cast<f4*>(p) = v; }

// ---------------- init: v = 1, flag = 1, ctr = 0 ----------------
__global__ __launch_bounds__(256) void k_init(float* __restrict__ v, int* __restrict__ flag,
                                              unsigned* __restrict__ ctr){
  int i = blockIdx.x * 256 + threadIdx.x;
  if (i < BB*NN*NN) v[i] = 1.0f;
  if (i == 0) { *flag = 1; *ctr = 0u; }
}

// ---------------- K1: x1[f][b][m][p] = sum_n Q1[b][n][m] * v[b][n][p] ----------------
// Q1 = (f==0 ? H1 : G1).  out 512x128, K=128.  grid(8,2,64)
__global__ __launch_bounds__(256) void k_x1(const float* __restrict__ H1,
                                            const float* __restrict__ G1,
                                            const float* __restrict__ v,
                                            float* __restrict__ x1,
                                            const int* __restrict__ flag){
  if (*flag == 0) return;
  const int bz = blockIdx.z;
  const int f = bz >> 5, b = bz & 31;
  const float* __restrict__ Q1 = f ? G1 : H1;
  const int mT = blockIdx.x * 64;
  const int pT = blockIdx.y * 64;
  const int tid = threadIdx.x;
  const int tx = tid & 15, ty = tid >> 4;
  const int lk = tid >> 4, lc = (tid & 15) * 4;

  __shared__ float As[16][68];
  __shared__ float Bs[16][68];
  float acc[4][4] = {};

  const float* Qb = Q1 + (size_t)b * NN * MM;  // [128][512]
  const float* vb = v  + (size_t)b * NN * NN;  // [128][128]

  for (int kt = 0; kt < NN; kt += 16) {
    f4 a  = ld4(Qb + (size_t)(kt + lk) * MM + mT + lc);
    f4 bv = ld4(vb + (size_t)(kt + lk) * NN + pT + lc);
    st4(&As[lk][lc], a);
    st4(&Bs[lk][lc], bv);
    __syncthreads();
    #pragma unroll
    for (int k = 0; k < 16; ++k) {
      f4 av = ld4(&As[k][ty*4]);
      f4 bw = ld4(&Bs[k][tx*4]);
      float ar[4] = {av.x, av.y, av.z, av.w};
      float br[4] = {bw.x, bw.y, bw.z, bw.w};
      #pragma unroll
      for (int i2 = 0; i2 < 4; ++i2)
        #pragma unroll
        for (int j = 0; j < 4; ++j)
          acc[i2][j] += ar[i2] * br[j];
    }
    __syncthreads();
  }
  float* xb = x1 + ((size_t)f*BB + b) * MM * NN;
  #pragma unroll
  for (int i2 = 0; i2 < 4; ++i2){
    int m = mT + ty*4 + i2;
    st4(xb + (size_t)m * NN + pT + tx*4,
        make_float4(acc[i2][0], acc[i2][1], acc[i2][2], acc[i2][3]));
  }
}

// ---------------- K2: y[f][b][m][q] = Mq[b][m][q] * sum_p x1[f][b][m][p]*Q2[b][p][q] ----------------
// Q2 = (f==0 ? H2 : G2). out 512x512, K=128. grid(8,8,64)
__global__ __launch_bounds__(256) void k_y(const float* __restrict__ H2,
                                           const float* __restrict__ G2,
                                           const float* __restrict__ x1,
                                           const float* __restrict__ Mq,
                                           float* __restrict__ y,
                                           const int* __restrict__ flag){
  if (*flag == 0) return;
  const int bz = blockIdx.z;
  const int f = bz >> 5, b = bz & 31;
  const float* __restrict__ Q2 = f ? G2 : H2;
  const int mT = blockIdx.x * 64;
  const int qT = blockIdx.y * 64;
  const int tid = threadIdx.x;
  const int tx = tid & 15, ty = tid >> 4;
  const int amm = tid >> 2, ak4 = (tid & 3) * 4;   // transposed A load
  const int lk = tid >> 4, lc = (tid & 15) * 4;    // direct B load

  __shared__ float As[16][68];
  __shared__ float Bs[16][68];
  float acc[4][4] = {};

  const float* xb = x1 + ((size_t)f*BB + b) * MM * NN;  // [512][128]
  const float* Qb = Q2 + (size_t)b * NN * MM;           // [128][512]

  for (int kt = 0; kt < NN; kt += 16) {
    f4 a = ld4(xb + (size_t)(mT + amm) * NN + kt + ak4);
    As[ak4+0][amm] = a.x; As[ak4+1][amm] = a.y; As[ak4+2][amm] = a.z; As[ak4+3][amm] = a.w;
    f4 bv = ld4(Qb + (size_t)(kt + lk) * MM + qT + lc);
    st4(&Bs[lk][lc], bv);
    __syncthreads();
    #pragma unroll
    for (int k = 0; k < 16; ++k) {
      f4 av = ld4(&As[k][ty*4]);
      f4 bw = ld4(&Bs[k][tx*4]);
      float ar[4] = {av.x, av.y, av.z, av.w};
      float br[4] = {bw.x, bw.y, bw.z, bw.w};
      #pragma unroll
      for (int i2 = 0; i2 < 4; ++i2)
        #pragma unroll
        for (int j = 0; j < 4; ++j)
          acc[i2][j] += ar[i2] * br[j];
    }
    __syncthreads();
  }
  const float* Mb = Mq + (size_t)b * MM * MM;
  float* yb = y + ((size_t)f*BB + b) * MM * MM;
  #pragma unroll
  for (int i2 = 0; i2 < 4; ++i2){
    int m = mT + ty*4 + i2;
    f4 mq = ld4(Mb + (size_t)m * MM + qT + tx*4);
    st4(yb + (size_t)m * MM + qT + tx*4,
        make_float4(acc[i2][0]*mq.x, acc[i2][1]*mq.y, acc[i2][2]*mq.z, acc[i2][3]*mq.w));
  }
}

// ---------------- K3: z1[kc][f][b][n][q] = sum_{m in chunk kc} P1[b][n][m]*y[f][b][m][q] ----------------
// P1 = (f==0 ? G1 : H1). out 128x512, K=256 per chunk. grid(2,8,128)
__global__ __launch_bounds__(256) void k_z1(const float* __restrict__ G1,
                                            const float* __restrict__ H1,
                                            const float* __restrict__ y,
                                            float* __restrict__ z1,
                                            const int* __restrict__ flag){
  if (*flag == 0) return;
  const int bz = blockIdx.z;
  const int b = bz & 31, f = (bz >> 5) & 1, kc = bz >> 6;
  const float* __restrict__ P1 = f ? H1 : G1;
  const int nT = blockIdx.x * 64;
  const int qT = blockIdx.y * 64;
  const int tid = threadIdx.x;
  const int tx = tid & 15, ty = tid >> 4;
  const int amm = tid >> 2, ak4 = (tid & 3) * 4;
  const int lk = tid >> 4, lc = (tid & 15) * 4;

  __shared__ float As[16][68];
  __shared__ float Bs[16][68];
  float acc[4][4] = {};

  const float* Pb = P1 + (size_t)b * NN * MM;            // [128][512]
  const float* yb = y + ((size_t)f*BB + b) * MM * MM;    // [512][512]
  const int k0 = kc * 256;

  for (int kt = 0; kt < 256; kt += 16) {
    f4 a = ld4(Pb + (size_t)(nT + amm) * MM + k0 + kt + ak4);
    As[ak4+0][amm] = a.x; As[ak4+1][amm] = a.y; As[ak4+2][amm] = a.z; As[ak4+3][amm] = a.w;
    f4 bv = ld4(yb + (size_t)(k0 + kt + lk) * MM + qT + lc);
    st4(&Bs[lk][lc], bv);
    __syncthreads();
    #pragma unroll
    for (int k = 0; k < 16; ++k) {
      f4 av = ld4(&As[k][ty*4]);
      f4 bw = ld4(&Bs[k][tx*4]);
      float ar[4] = {av.x, av.y, av.z, av.w};
      float br[4] = {bw.x, bw.y, bw.z, bw.w};
      #pragma unroll
      for (int i2 = 0; i2 < 4; ++i2)
        #pragma unroll
        for (int j = 0; j < 4; ++j)
          acc[i2][j] += ar[i2] * br[j];
    }
    __syncthreads();
  }
  float* zb = z1 + (((size_t)kc*2 + f)*BB + b) * NN * MM;
  #pragma unroll
  for (int i2 = 0; i2 < 4; ++i2){
    int n = nT + ty*4 + i2;
    st4(zb + (size_t)n * MM + qT + tx*4,
        make_float4(acc[i2][0], acc[i2][1], acc[i2][2], acc[i2][3]));
  }
}

// ---------------- K4: z2p[f][b][c][n][p] = sum_{q in chunk c} (z1a+z1b)[f][b][n][q]*P2[b][p][q] ----------------
// P2 = (f==0 ? G2 : H2). out 128x128 per (f,b,c), K=128 per chunk. grid(2,2,256)
__global__ __launch_bounds__(256) void k_z2(const float* __restrict__ G2,
                                            const float* __restrict__ H2,
                                            const float* __restrict__ z1,
                                            float* __restrict__ z2p,
                                            const int* __restrict__ flag){
  if (*flag == 0) return;
  const int bz = blockIdx.z;
  const int c = bz & 3, f = (bz >> 2) & 1, b = bz >> 3;
  const float* __restrict__ P2 = f ? H2 : G2;
  const int nT = blockIdx.x * 64;
  const int pT = blockIdx.y * 64;
  const int tid = threadIdx.x;
  const int tx = tid & 15, ty = tid >> 4;
  const int amm = tid >> 2, ak4 = (tid & 3) * 4;

  __shared__ float As[16][68];
  __shared__ float Bs[16][68];
  float acc[4][4] = {};

  const float* za = z1 + (((size_t)0*2 + f)*BB + b) * NN * MM;  // [128][512]
  const float* zb = z1 + (((size_t)1*2 + f)*BB + b) * NN * MM;  // [128][512]
  const float* Pb = P2 + (size_t)b * NN * MM;                    // [128][512]
  const int k0 = c * 128;

  for (int kt = 0; kt < 128; kt += 16) {
    f4 a0 = ld4(za + (size_t)(nT + amm) * MM + k0 + kt + ak4);
    f4 a1 = ld4(zb + (size_t)(nT + amm) * MM + k0 + kt + ak4);
    As[ak4+0][amm] = a0.x + a1.x; As[ak4+1][amm] = a0.y + a1.y;
    As[ak4+2][amm] = a0.z + a1.z; As[ak4+3][amm] = a0.w + a1.w;
    f4 bv = ld4(Pb + (size_t)(pT + amm) * MM + k0 + kt + ak4);
    Bs[ak4+0][amm] = bv.x; Bs[ak4+1][amm] = bv.y; Bs[ak4+2][amm] = bv.z; Bs[ak4+3][amm] = bv.w;
    __syncthreads();
    #pragma unroll
    for (int k = 0; k < 16; ++k) {
      f4 av = ld4(&As[k][ty*4]);
      f4 bw = ld4(&Bs[k][tx*4]);
      float ar[4] = {av.x, av.y, av.z, av.w};
      float br[4] = {bw.x, bw.y, bw.z, bw.w};
      #pragma unroll
      for (int i2 = 0; i2 < 4; ++i2)
        #pragma unroll
        for (int j = 0; j < 4; ++j)
          acc[i2][j] += ar[i2] * br[j];
    }
    __syncthreads();
  }
  float* ob = z2p + (((size_t)f*BB + b)*4 + c) * NN * NN;
  #pragma unroll
  for (int i2 = 0; i2 < 4; ++i2){
    int n = nT + ty*4 + i2;
    st4(ob + (size_t)n * NN + pT + tx*4,
        make_float4(acc[i2][0], acc[i2][1], acc[i2][2], acc[i2][3]));
  }
}

// ---------------- K5: fused: t = 0.5*sum(z2p) + Mp.*v ; nrm ; u=t/nrm ; diff ; v=u ; flag ----------------
// grid(32), block(1024). One block per batch.
__global__ __launch_bounds__(1024) void k_normfuse(const float* __restrict__ z2p,
                                                   const float* __restrict__ Mp,
                                                   float* __restrict__ v,
                                                   float* __restrict__ diff2,
                                                   int* __restrict__ flag,
                                                   unsigned* __restrict__ ctr){
  if (*flag == 0) return;
  const int b = blockIdx.x;
  const int tid = threadIdx.x;
  const size_t base = (size_t)b * NN * NN;

  float tv[16], vv[16];
  float n2 = 0.f;
  #pragma unroll
  for (int i = 0; i < 16; ++i) {
    int e = tid + i*1024;
    float z = 0.f;
    #pragma unroll
    for (int f = 0; f < 2; ++f)
      #pragma unroll
      for (int c = 0; c < 4; ++c)
        z += z2p[(((size_t)f*BB + b)*4 + c)*NN*NN + e];
    vv[i] = v[base + e];
    tv[i] = 0.5f*z + Mp[base + e]*vv[i];
    n2 += tv[i]*tv[i];
  }

  __shared__ float red[1024];
  red[tid] = n2; __syncthreads();
  for (int s = 512; s > 0; s >>= 1){ if (tid < s) red[tid] += red[tid+s]; __syncthreads(); }
  float nrm2 = red[0];
  __syncthreads();

  float rn = (nrm2 == 0.f) ? 0.f : 1.0f / sqrtf(nrm2);
  float d2 = 0.f;
  #pragma unroll
  for (int i = 0; i < 16; ++i) {
    int e = tid + i*1024;
    float u = tv[i] * rn;
    float d = u - vv[i];
    d2 += d*d;
    v[base + e] = u;
  }

  red[tid] = d2; __syncthreads();
  for (int s = 512; s > 0; s >>= 1){ if (tid < s) red[tid] += red[tid+s]; __syncthreads(); }

  if (tid == 0) {
    diff2[b] = red[0];
    __threadfence();
    unsigned old = atomicAdd(ctr, 1u);
    if (old == (unsigned)(BB - 1)) {
      __threadfence();
      int any = 0;
      #pragma unroll
      for (int j = 0; j < BB; ++j) any |= (diff2[j] >= EPS2) ? 1 : 0;
      if (!any) *flag = 0;
      *ctr = 0u;
    }
  }
}

extern "C" void kernel_launch(void* const* d_in, const int* in_sizes, int n_in,
                              void* d_out, int out_size, void* d_ws, size_t ws_size,
                              hipStream_t stream) {
  const float* Mp = (const float*)d_in[0];
  const float* Mq = (const float*)d_in[1];
  const float* G1 = (const float*)d_in[2];
  const float* G2 = (const float*)d_in[3];
  const float* H1 = (const float*)d_in[4];
  const float* H2 = (const float*)d_in[5];
  float* v = (float*)d_out;

  float* ws = (float*)d_ws;
  // x1 [2][32][512][128] aliases z2p [2][32][4][128][128]  (disjoint live ranges)
  float* x1  = ws;                               // 4,194,304 floats
  float* z2p = ws;                               // alias
  float* y   = ws + 4194304;                     // 16,777,216 floats ([2][32][512][512])
  float* z1  = y + 16777216;                     // 8,388,608 floats ([2kc][2f][32][128][512])
  float* diff2 = z1 + 8388608;                   // 32 floats
  int*  flag = (int*)(diff2 + 32);
  unsigned* ctr = (unsigned*)(flag + 1);

  k_init<<<dim3(2048), 256, 0, stream>>>(v, flag, ctr);

  for (int it = 0; it < NITER; ++it) {
    k_x1<<<dim3(8, 2, 64), 256, 0, stream>>>(H1, G1, v, x1, flag);
    k_y <<<dim3(8, 8, 64), 256, 0, stream>>>(H2, G2, x1, Mq, y, flag);
    k_z1<<<dim3(2, 8, 128), 256, 0, stream>>>(G1, H1, y, z1, flag);
    k_z2<<<dim3(2, 2, 256), 256, 0, stream>>>(G2, H2, z1, z2p, flag);
    k_normfuse<<<dim3(32), 1024, 0, stream>>>(z2p, Mp, v, diff2, flag, ctr);
  }
}

// Round 3
// 594.506 us; speedup vs baseline: 1.3073x; 1.1083x over previous
//
#include <hip/hip_runtime.h>

#define BB 32
#define NITER 15
#define EPS2 1e-12f   // (1e-6)^2

typedef unsigned short u16;
typedef __attribute__((ext_vector_type(8))) short  bf16x8;  // 8 bf16 = 4 VGPR (MFMA A/B frag)
typedef __attribute__((ext_vector_type(4))) float  f32x4;   // MFMA C/D frag
typedef __attribute__((ext_vector_type(8))) u16    u16x8;
typedef __attribute__((ext_vector_type(4))) u16    u16x4;

__device__ __forceinline__ u16 f2bf(float x){            // RNE fp32 -> bf16 bits
  unsigned u = __float_as_uint(x);
  return (u16)((u + 0x7FFFu + ((u>>16)&1u)) >> 16);
}
__device__ __forceinline__ float bf2f(u16 h){ return __uint_as_float(((unsigned)h)<<16); }

// ============ init: v = 1, vT planes = (1,0), flag = 1, ctr = 0 ============
__global__ __launch_bounds__(256) void k_initv(float* __restrict__ v, u16* __restrict__ vTp,
                                               int* __restrict__ flag, unsigned* __restrict__ ctr){
  int gid = blockIdx.x*256 + threadIdx.x;               // grid 512 -> 131072 threads
  #pragma unroll
  for (int i = 0; i < 4; ++i){
    int e = gid*4 + i;
    if (e < BB*16384) v[e] = 1.0f;
  }
  #pragma unroll
  for (int i = 0; i < 8; ++i){
    int e = gid*8 + i;
    if (e < BB*32768) vTp[e] = ((e>>14)&1) ? (u16)0 : (u16)0x3F80;  // hi plane=1.0, lo=0
  }
  if (gid == 0){ *flag = 1; *ctr = 0u; }
}

// ============ prep: split (no transpose)  in[128][512] -> planes [128][512] ============
// t: 0:G1->P1 f0, 1:H1->P1 f1, 2:G2->P2 f0, 3:H2->P2 f1.  grid(32, 32, 4)
__global__ __launch_bounds__(256) void k_prep(const float* __restrict__ G1, const float* __restrict__ H1,
                                              const float* __restrict__ G2, const float* __restrict__ H2,
                                              u16* __restrict__ P1p, u16* __restrict__ P2p){
  const int t = blockIdx.z, b = blockIdx.y;
  const float* src = (t==0?G1: t==1?H1: t==2?G2:H2) + (size_t)b*65536;
  u16* dst = (t<2? P1p : P2p) + ((size_t)((t&1)*BB + b))*2*65536;
  const int e0 = (blockIdx.x*256 + threadIdx.x)*8;
  float4 v0 = *(const float4*)(src + e0);
  float4 v1 = *(const float4*)(src + e0 + 4);
  float xs[8] = {v0.x,v0.y,v0.z,v0.w,v1.x,v1.y,v1.z,v1.w};
  u16x8 h, l;
  #pragma unroll
  for (int i = 0; i < 8; ++i){
    u16 hi = f2bf(xs[i]); h[i] = hi; l[i] = f2bf(xs[i] - bf2f(hi));
  }
  *(u16x8*)(dst + e0) = h;
  *(u16x8*)(dst + 65536 + e0) = l;
}

// ============ prepT: transpose + split  in[128][512] -> planes [512][128] ============
// t: 0:H1->Q1T f0, 1:G1->Q1T f1, 2:H2->Q2T f0, 3:G2->Q2T f1.  grid(16, 4, 128) z=b*4+t
__global__ __launch_bounds__(256) void k_prepT(const float* __restrict__ H1, const float* __restrict__ G1,
                                               const float* __restrict__ H2, const float* __restrict__ G2,
                                               u16* __restrict__ Q1T, u16* __restrict__ Q2T){
  const int t = blockIdx.z & 3, b = blockIdx.z >> 2;
  const float* src = (t==0?H1: t==1?G1: t==2?H2:G2) + (size_t)b*65536;   // [128 n][512 m]
  u16* dst = (t<2? Q1T : Q2T) + ((size_t)((t&1)*BB + b))*2*65536;        // [512 m][128 n]
  const int mt = blockIdx.x*32, nt = blockIdx.y*32;
  __shared__ float ts[32][33];
  const int r = threadIdx.x>>3, c4 = (threadIdx.x&7)*4;
  float4 vv = *(const float4*)(src + (size_t)(nt+r)*512 + mt + c4);
  ts[r][c4+0]=vv.x; ts[r][c4+1]=vv.y; ts[r][c4+2]=vv.z; ts[r][c4+3]=vv.w;
  __syncthreads();
  u16x4 h, l;
  #pragma unroll
  for (int i = 0; i < 4; ++i){
    float x = ts[c4+i][r];                 // = src[nt+c4+i][mt+r]
    u16 hi = f2bf(x); h[i] = hi; l[i] = f2bf(x - bf2f(hi));
  }
  size_t o = (size_t)(mt + r)*128 + nt + c4;
  *(u16x4*)(dst + o) = h;
  *(u16x4*)(dst + 65536 + o) = l;
}

// ============ prep MqT: fp32 transpose Mq[b][m][q] -> MqT[b][q][m].  grid(16,16,32) ============
__global__ __launch_bounds__(256) void k_prepM(const float* __restrict__ Mq, float* __restrict__ MqT){
  const int b = blockIdx.z;
  const float* src = Mq + (size_t)b*262144;
  float* dst = MqT + (size_t)b*262144;
  const int mt = blockIdx.x*32, qt = blockIdx.y*32;
  __shared__ float ts[32][33];
  const int r = threadIdx.x>>3, c4 = (threadIdx.x&7)*4;
  float4 vv = *(const float4*)(src + (size_t)(mt+r)*512 + qt + c4);
  ts[r][c4+0]=vv.x; ts[r][c4+1]=vv.y; ts[r][c4+2]=vv.z; ts[r][c4+3]=vv.w;
  __syncthreads();
  float4 ov = make_float4(ts[c4+0][r], ts[c4+1][r], ts[c4+2][r], ts[c4+3][r]);
  *(float4*)(dst + (size_t)(qt + r)*512 + mt + c4) = ov;   // dst[q][m] = src[m][q]
}

// ============ generic split-bf16 MFMA GEMM: C[r][c] = sum_k A[r][k]*B[c][k] ============
// S=0: x1[m][p]   = Q1T[m][n]  . vT[p][n]    M=512 N=128 K=128            -> x1 planes
// S=1: yT[q][m]   = Q2T[q][p]  . x1[m][p]    M=512 N=512 K=128  (*MqT)    -> yT planes
// S=2: z1[n][q]   = P1[n][m]   . yT[q][m]    M=128 N=512 K=512            -> z1 planes
// S=3: z2c[n][p]  = z1[n][q0+] . P2[p][q0+]  M=128 N=128 K=128 chunk c    -> f32 partials
template<int S>
__global__ __launch_bounds__(256) void k_gemm(const u16* __restrict__ A,
                                              const u16* __restrict__ B,
                                              u16* __restrict__ Co,
                                              float* __restrict__ Cf,
                                              const float* __restrict__ MqT,
                                              const int* __restrict__ flag){
  if (*flag == 0) return;
  constexpr int KD   = (S>=2) ? 512 : 128;   // K storage stride (both operands)
  constexpr int KLEN = (S==2) ? 512 : 128;   // K summed this launch
  int bz = blockIdx.z;
  int f, b, c = 0;
  if (S==3){ f = bz>>7; b = (bz>>2)&31; c = bz&3; }
  else     { f = bz>>5; b = bz&31; }
  const int rowBlk = blockIdx.x*128;
  const int colBlk = blockIdx.y*128;
  const int kBase  = (S==3) ? c*128 : 0;

  const size_t fb = (size_t)(f*BB + b);
  const u16* Ah = A + fb*2*65536;
  const u16* Al = Ah + 65536;
  size_t bOff, bPl;
  if      (S==0){ bOff = (size_t)b*2*16384;  bPl = 16384;  }
  else if (S==2){ bOff = fb*2*262144;        bPl = 262144; }
  else          { bOff = fb*2*65536;         bPl = 65536;  }
  const u16* Bh = B + bOff;
  const u16* Bl = Bh + bPl;

  const int tid = threadIdx.x;
  const int wid = tid>>6, lane = tid&63;
  const int wr = (wid>>1)*64, wc = (wid&1)*64;
  const int l15 = lane&15, g = lane>>4;

  __shared__ __align__(16) u16 sm[4][128*40];   // 4 planes, 128 rows x 32 k, pitch 40 (80B)

  f32x4 acc[4][4];
  #pragma unroll
  for (int i=0;i<4;++i)
    #pragma unroll
    for (int j=0;j<4;++j) acc[i][j] = (f32x4){0.f,0.f,0.f,0.f};

  for (int kt = 0; kt < KLEN; kt += 32){
    // ---- stage 4 planes: 512 chunks of 16B each, 2 chunks/thread/plane ----
    #pragma unroll
    for (int i = 0; i < 2; ++i){
      int ch  = tid*2 + i;
      int row = ch >> 2, seg = ch & 3;
      size_t gk = (size_t)(kBase + kt + seg*8);
      size_t ga = (size_t)(rowBlk + row)*KD + gk;
      size_t gb = (size_t)(colBlk + row)*KD + gk;
      u16x8 vah = *(const u16x8*)(Ah + ga);
      u16x8 val = *(const u16x8*)(Al + ga);
      u16x8 vbh = *(const u16x8*)(Bh + gb);
      u16x8 vbl = *(const u16x8*)(Bl + gb);
      int lo = row*40 + seg*8;
      *(u16x8*)&sm[0][lo] = vah;
      *(u16x8*)&sm[1][lo] = val;
      *(u16x8*)&sm[2][lo] = vbh;
      *(u16x8*)&sm[3][lo] = vbl;
    }
    __syncthreads();
    // ---- fragments + 48 MFMA ----
    bf16x8 ah[4], al[4];
    #pragma unroll
    for (int i=0;i<4;++i){
      int r = wr + i*16 + l15;
      ah[i] = *(const bf16x8*)&sm[0][r*40 + g*8];
      al[i] = *(const bf16x8*)&sm[1][r*40 + g*8];
    }
    #pragma unroll
    for (int j=0;j<4;++j){
      int cc = wc + j*16 + l15;
      bf16x8 bh = *(const bf16x8*)&sm[2][cc*40 + g*8];
      bf16x8 bl = *(const bf16x8*)&sm[3][cc*40 + g*8];
      #pragma unroll
      for (int i=0;i<4;++i){
        acc[i][j] = __builtin_amdgcn_mfma_f32_16x16x32_bf16(ah[i], bh, acc[i][j], 0,0,0);
        acc[i][j] = __builtin_amdgcn_mfma_f32_16x16x32_bf16(al[i], bh, acc[i][j], 0,0,0);
        acc[i][j] = __builtin_amdgcn_mfma_f32_16x16x32_bf16(ah[i], bl, acc[i][j], 0,0,0);
      }
    }
    __syncthreads();
  }

  // ---- epilogue.  C element: row = rowBlk+wr+i*16+g*4+r, col = colBlk+wc+j*16+l15 ----
  if (S==3){
    float* Cb = Cf + (fb*4 + (size_t)c)*16384;
    #pragma unroll
    for (int i=0;i<4;++i)
      #pragma unroll
      for (int j=0;j<4;++j)
        #pragma unroll
        for (int r=0;r<4;++r){
          int ro = wr + i*16 + g*4 + r, co = wc + j*16 + l15;
          Cb[ro*128 + co] = acc[i][j][r];
        }
  } else if (S==1){
    u16* Ch = Co + fb*2*262144;
    u16* Cl = Ch + 262144;
    const float* Mb = MqT + (size_t)b*262144;
    #pragma unroll
    for (int i=0;i<4;++i)
      #pragma unroll
      for (int j=0;j<4;++j)
        #pragma unroll
        for (int r=0;r<4;++r){
          int ro = rowBlk + wr + i*16 + g*4 + r, co = colBlk + wc + j*16 + l15;
          float x = acc[i][j][r] * Mb[(size_t)ro*512 + co];
          u16 hi = f2bf(x);
          Ch[(size_t)ro*512 + co] = hi;
          Cl[(size_t)ro*512 + co] = f2bf(x - bf2f(hi));
        }
  } else {
    constexpr int LDC = (S==0) ? 128 : 512;
    u16* Ch = Co + fb*2*65536;
    u16* Cl = Ch + 65536;
    #pragma unroll
    for (int i=0;i<4;++i)
      #pragma unroll
      for (int j=0;j<4;++j)
        #pragma unroll
        for (int r=0;r<4;++r){
          int ro = rowBlk + wr + i*16 + g*4 + r, co = colBlk + wc + j*16 + l15;
          float x = acc[i][j][r];
          u16 hi = f2bf(x);
          Ch[(size_t)ro*LDC + co] = hi;
          Cl[(size_t)ro*LDC + co] = f2bf(x - bf2f(hi));
        }
  }
}

// ============ fused: t = 0.5*sum(z2p) + Mp.*v ; nrm ; u ; diff ; v=u ; vT planes ; flag ============
// grid(32), block(1024)
__global__ __launch_bounds__(1024) void k_nf(const float* __restrict__ z2p,
                                             const float* __restrict__ Mp,
                                             float* __restrict__ v,
                                             u16* __restrict__ vTp,
                                             float* __restrict__ diff2,
                                             int* __restrict__ flag,
                                             unsigned* __restrict__ ctr){
  if (*flag == 0) return;
  const int b = blockIdx.x, tid = threadIdx.x;
  const size_t base = (size_t)b*16384;
  __shared__ float sred[1024];
  __shared__ float su[128][129];

  float tv[16], vv[16];
  float n2 = 0.f;
  #pragma unroll
  for (int i = 0; i < 16; ++i){
    int e = tid + i*1024;
    float z = 0.f;
    #pragma unroll
    for (int f = 0; f < 2; ++f)
      #pragma unroll
      for (int cc = 0; cc < 4; ++cc)
        z += z2p[(((size_t)f*BB + b)*4 + cc)*16384 + e];
    vv[i] = v[base + e];
    tv[i] = 0.5f*z + Mp[base + e]*vv[i];
    n2 += tv[i]*tv[i];
  }
  sred[tid] = n2; __syncthreads();
  for (int s = 512; s > 0; s >>= 1){ if (tid < s) sred[tid] += sred[tid+s]; __syncthreads(); }
  float nrm2 = sred[0];
  __syncthreads();

  float rn = (nrm2 == 0.f) ? 0.f : 1.0f / sqrtf(nrm2);
  float d2 = 0.f;
  #pragma unroll
  for (int i = 0; i < 16; ++i){
    int e = tid + i*1024;
    float u = tv[i] * rn;
    float d = u - vv[i];
    d2 += d*d;
    v[base + e] = u;
    su[e>>7][e&127] = u;
  }
  sred[tid] = d2; __syncthreads();
  for (int s = 512; s > 0; s >>= 1){ if (tid < s) sred[tid] += sred[tid+s]; __syncthreads(); }

  // vT planes: vT[p][n] = u[n][p]
  u16* Ch = vTp + (size_t)b*32768;
  u16* Cl = Ch + 16384;
  #pragma unroll
  for (int i = 0; i < 16; ++i){
    int e = tid + i*1024;                  // e = p*128 + n
    float x = su[e & 127][e >> 7];
    u16 hi = f2bf(x);
    Ch[e] = hi;
    Cl[e] = f2bf(x - bf2f(hi));
  }

  if (tid == 0){
    diff2[b] = sred[0];
    __threadfence();
    unsigned old = atomicAdd(ctr, 1u);
    if (old == (unsigned)(BB - 1)){
      __threadfence();
      int any = 0;
      #pragma unroll
      for (int j = 0; j < BB; ++j) any |= (diff2[j] >= EPS2) ? 1 : 0;
      if (!any) *flag = 0;
      *ctr = 0u;
    }
  }
}

extern "C" void kernel_launch(void* const* d_in, const int* in_sizes, int n_in,
                              void* d_out, int out_size, void* d_ws, size_t ws_size,
                              hipStream_t stream) {
  const float* Mp = (const float*)d_in[0];
  const float* Mq = (const float*)d_in[1];
  const float* G1 = (const float*)d_in[2];
  const float* G2 = (const float*)d_in[3];
  const float* H1 = (const float*)d_in[4];
  const float* H2 = (const float*)d_in[5];
  float* v = (float*)d_out;

  u16* Q1T = (u16*)d_ws;                   //  [2][32][2][512][128]
  u16* Q2T = Q1T + 8388608;                //  [2][32][2][512][128]
  u16* P1p = Q2T + 8388608;                //  [2][32][2][128][512]
  u16* P2p = P1p + 8388608;                //  [2][32][2][128][512]
  u16* x1p = P2p + 8388608;                //  [2][32][2][512][128]
  u16* yTp = x1p + 8388608;                //  [2][32][2][512][512]
  u16* z1p = yTp + 33554432;               //  [2][32][2][128][512]
  u16* vTp = z1p + 8388608;                //  [32][2][128][128]
  float* MqT  = (float*)(vTp + 1048576);   //  [32][512][512]
  float* z2p  = MqT + 8388608;             //  [2][32][4][128][128]
  float* diff2 = z2p + 4194304;            //  [32]
  int* flag = (int*)(diff2 + 32);
  unsigned* ctr = (unsigned*)(flag + 1);

  k_initv<<<dim3(512), 256, 0, stream>>>(v, vTp, flag, ctr);
  k_prep <<<dim3(32, 32, 4),  256, 0, stream>>>(G1, H1, G2, H2, P1p, P2p);
  k_prepT<<<dim3(16, 4, 128), 256, 0, stream>>>(H1, G1, H2, G2, Q1T, Q2T);
  k_prepM<<<dim3(16, 16, 32), 256, 0, stream>>>(Mq, MqT);

  for (int it = 0; it < NITER; ++it) {
    k_gemm<0><<<dim3(4, 1, 64),  256, 0, stream>>>(Q1T, vTp, x1p, nullptr, nullptr, flag);
    k_gemm<1><<<dim3(4, 4, 64),  256, 0, stream>>>(Q2T, x1p, yTp, nullptr, MqT,     flag);
    k_gemm<2><<<dim3(1, 4, 64),  256, 0, stream>>>(P1p, yTp, z1p, nullptr, nullptr, flag);
    k_gemm<3><<<dim3(1, 1, 256), 256, 0, stream>>>(z1p, P2p, nullptr, z2p, nullptr, flag);
    k_nf<<<dim3(32), 1024, 0, stream>>>(z2p, Mp, v, vTp, diff2, flag, ctr);
  }
}

// Round 4
// 532.360 us; speedup vs baseline: 1.4599x; 1.1167x over previous
//
#include <hip/hip_runtime.h>

#define BB 32
#define NITER 15
#define EPS2 1e-12f   // (1e-6)^2

typedef unsigned short u16;
typedef __attribute__((ext_vector_type(8))) short  bf16x8;  // 8 bf16 = 4 VGPR (MFMA A/B frag)
typedef __attribute__((ext_vector_type(4))) float  f32x4;   // MFMA C/D frag
typedef __attribute__((ext_vector_type(8))) u16    u16x8;
typedef __attribute__((ext_vector_type(4))) u16    u16x4;

__device__ __forceinline__ u16 f2bf(float x){            // RNE fp32 -> bf16 bits
  unsigned u = __float_as_uint(x);
  return (u16)((u + 0x7FFFu + ((u>>16)&1u)) >> 16);
}
__device__ __forceinline__ float bf2f(u16 h){ return __uint_as_float(((unsigned)h)<<16); }

// ============ init: v = 1, vT planes = (1,0), flag = 1, ctr = 0 ============
__global__ __launch_bounds__(256) void k_initv(float* __restrict__ v, u16* __restrict__ vTp,
                                               int* __restrict__ flag, unsigned* __restrict__ ctr){
  int gid = blockIdx.x*256 + threadIdx.x;               // grid 512 -> 131072 threads
  #pragma unroll
  for (int i = 0; i < 4; ++i){
    int e = gid*4 + i;
    if (e < BB*16384) v[e] = 1.0f;
  }
  #pragma unroll
  for (int i = 0; i < 8; ++i){
    int e = gid*8 + i;
    if (e < BB*32768) vTp[e] = ((e>>14)&1) ? (u16)0 : (u16)0x3F80;  // hi plane=1.0, lo=0
  }
  if (gid == 0){ *flag = 1; *ctr = 0u; }
}

// ============ prep: split (no transpose)  in[128][512] -> planes [128][512] ============
// t: 0:G1->P1 f0, 1:H1->P1 f1, 2:G2->P2 f0, 3:H2->P2 f1.  grid(32, 32, 4)
__global__ __launch_bounds__(256) void k_prep(const float* __restrict__ G1, const float* __restrict__ H1,
                                              const float* __restrict__ G2, const float* __restrict__ H2,
                                              u16* __restrict__ P1p, u16* __restrict__ P2p){
  const int t = blockIdx.z, b = blockIdx.y;
  const float* src = (t==0?G1: t==1?H1: t==2?G2:H2) + (size_t)b*65536;
  u16* dst = (t<2? P1p : P2p) + ((size_t)((t&1)*BB + b))*2*65536;
  const int e0 = (blockIdx.x*256 + threadIdx.x)*8;
  float4 v0 = *(const float4*)(src + e0);
  float4 v1 = *(const float4*)(src + e0 + 4);
  float xs[8] = {v0.x,v0.y,v0.z,v0.w,v1.x,v1.y,v1.z,v1.w};
  u16x8 h, l;
  #pragma unroll
  for (int i = 0; i < 8; ++i){
    u16 hi = f2bf(xs[i]); h[i] = hi; l[i] = f2bf(xs[i] - bf2f(hi));
  }
  *(u16x8*)(dst + e0) = h;
  *(u16x8*)(dst + 65536 + e0) = l;
}

// ============ prepT: transpose + split  in[128][512] -> planes [512][128] ============
// t: 0:H1->Q1T f0, 1:G1->Q1T f1, 2:H2->Q2T f0, 3:G2->Q2T f1.  grid(16, 4, 128) z=b*4+t
__global__ __launch_bounds__(256) void k_prepT(const float* __restrict__ H1, const float* __restrict__ G1,
                                               const float* __restrict__ H2, const float* __restrict__ G2,
                                               u16* __restrict__ Q1T, u16* __restrict__ Q2T){
  const int t = blockIdx.z & 3, b = blockIdx.z >> 2;
  const float* src = (t==0?H1: t==1?G1: t==2?H2:G2) + (size_t)b*65536;   // [128 n][512 m]
  u16* dst = (t<2? Q1T : Q2T) + ((size_t)((t&1)*BB + b))*2*65536;        // [512 m][128 n]
  const int mt = blockIdx.x*32, nt = blockIdx.y*32;
  __shared__ float ts[32][33];
  const int r = threadIdx.x>>3, c4 = (threadIdx.x&7)*4;
  float4 vv = *(const float4*)(src + (size_t)(nt+r)*512 + mt + c4);
  ts[r][c4+0]=vv.x; ts[r][c4+1]=vv.y; ts[r][c4+2]=vv.z; ts[r][c4+3]=vv.w;
  __syncthreads();
  u16x4 h, l;
  #pragma unroll
  for (int i = 0; i < 4; ++i){
    float x = ts[c4+i][r];                 // = src[nt+c4+i][mt+r]
    u16 hi = f2bf(x); h[i] = hi; l[i] = f2bf(x - bf2f(hi));
  }
  size_t o = (size_t)(mt + r)*128 + nt + c4;
  *(u16x4*)(dst + o) = h;
  *(u16x4*)(dst + 65536 + o) = l;
}

// ============ prep MqT: transpose + split Mq[b][m][q] -> MqT planes [b][2][512 q][512 m] ============
// grid(16,16,32)
__global__ __launch_bounds__(256) void k_prepM(const float* __restrict__ Mq, u16* __restrict__ MqTp){
  const int b = blockIdx.z;
  const float* src = Mq + (size_t)b*262144;
  u16* Dh = MqTp + (size_t)b*2*262144;
  u16* Dl = Dh + 262144;
  const int mt = blockIdx.x*32, qt = blockIdx.y*32;
  __shared__ float ts[32][33];
  const int r = threadIdx.x>>3, c4 = (threadIdx.x&7)*4;
  float4 vv = *(const float4*)(src + (size_t)(mt+r)*512 + qt + c4);
  ts[r][c4+0]=vv.x; ts[r][c4+1]=vv.y; ts[r][c4+2]=vv.z; ts[r][c4+3]=vv.w;
  __syncthreads();
  u16x4 h, l;
  #pragma unroll
  for (int i = 0; i < 4; ++i){
    float x = ts[c4+i][r];                 // = src[mt+c4+i][qt+r] = Mq[m][q] at q=qt+r
    u16 hi = f2bf(x); h[i] = hi; l[i] = f2bf(x - bf2f(hi));
  }
  size_t o = (size_t)(qt + r)*512 + mt + c4;   // MqT[q][m]
  *(u16x4*)(Dh + o) = h;
  *(u16x4*)(Dl + o) = l;
}

// ============ generic split-bf16 MFMA GEMM: C[r][c] = sum_k A[r][k]*B[c][k] ============
// S=0: x1[m][p]   = Q1T[m][n]  . vT[p][n]    M=512 N=128 K=128            -> x1 planes
// S=1: yT[q][m]   = Q2T[q][p]  . x1[m][p]    M=512 N=512 K=128  (*MqT)    -> yT planes
// S=2: z1[n][q]   = P1[n][m]   . yT[q][m]    M=128 N=512 K=512            -> z1 planes
// S=3: z2c[n][p]  = z1[n][q0+] . P2[p][q0+]  M=128 N=128 K=128 chunk c    -> f32 partials
// 1-D grid; bijective XCD swizzle: blocks of the same (f,b) land on one XCD.
template<int S>
__global__ __launch_bounds__(256) void k_gemm(const u16* __restrict__ A,
                                              const u16* __restrict__ B,
                                              u16* __restrict__ Co,
                                              float* __restrict__ Cf,
                                              const u16* __restrict__ MqTp,
                                              const int* __restrict__ flag){
  if (*flag == 0) return;
  constexpr int KD   = (S>=2) ? 512 : 128;   // K storage stride (both operands)
  constexpr int KLEN = (S==2) ? 512 : 128;   // K summed this launch
  constexpr int NBLK = (S==1) ? 1024 : 256;

  // XCD-aware bijective swizzle: flat -> (xcd, slot) -> contiguous work per XCD
  const int flat = blockIdx.x;
  const int work = (flat & 7) * (NBLK/8) + (flat >> 3);

  int fb, rowBlk, colBlk, kBase = 0;
  if      (S==0){ fb = work>>2; rowBlk = (work&3)*128; colBlk = 0; }
  else if (S==1){ fb = work>>4; rowBlk = (work&3)*128; colBlk = ((work>>2)&3)*128; }
  else if (S==2){ fb = work>>2; rowBlk = 0;            colBlk = (work&3)*128; }
  else          { int b = work>>3, f = (work>>2)&1; fb = f*BB + b;
                  rowBlk = 0; colBlk = 0; kBase = (work&3)*128; }
  const int b = fb & 31;

  const u16* Ah = A + (size_t)fb*2*65536;
  const u16* Al = Ah + 65536;
  size_t bOff, bPl;
  if      (S==0){ bOff = (size_t)b*2*16384;          bPl = 16384;  }
  else if (S==2){ bOff = (size_t)fb*2*262144;        bPl = 262144; }
  else          { bOff = (size_t)fb*2*65536;         bPl = 65536;  }
  const u16* Bh = B + bOff;
  const u16* Bl = Bh + bPl;

  const int tid = threadIdx.x;
  const int wid = tid>>6, lane = tid&63;
  const int wr = (wid>>1)*64, wc = (wid&1)*64;
  const int l15 = lane&15, g = lane>>4;

  __shared__ __align__(16) u16 sm[4][128*40];   // 4 planes, 128 rows x 32 k, pitch 40 (80B)

  f32x4 acc[4][4];
  #pragma unroll
  for (int i=0;i<4;++i)
    #pragma unroll
    for (int j=0;j<4;++j) acc[i][j] = (f32x4){0.f,0.f,0.f,0.f};

  // staging addresses for this thread (2 chunks x 4 planes)
  const int ch0 = tid*2;
  const int row0 = ch0 >> 2, seg0 = (ch0 & 3);
  // chunk i: row = row0 + (i? ((ch0+1)>>2)-row0 : 0) ... ch0 even => chunks (row0,seg0),(row0,seg0+1) or cross-row
  // simpler: recompute per i below.

  u16x8 pre[4][2];

  // ---- prologue: load kt=0 into regs ----
  #pragma unroll
  for (int i = 0; i < 2; ++i){
    int ch = tid*2 + i;
    int row = ch >> 2, seg = ch & 3;
    size_t gk = (size_t)(kBase + 0 + seg*8);
    size_t ga = (size_t)(rowBlk + row)*KD + gk;
    size_t gb = (size_t)(colBlk + row)*KD + gk;
    pre[0][i] = *(const u16x8*)(Ah + ga);
    pre[1][i] = *(const u16x8*)(Al + ga);
    pre[2][i] = *(const u16x8*)(Bh + gb);
    pre[3][i] = *(const u16x8*)(Bl + gb);
  }

  for (int kt = 0; kt < KLEN; kt += 32){
    // ---- commit prefetched regs to LDS ----
    #pragma unroll
    for (int i = 0; i < 2; ++i){
      int ch = tid*2 + i;
      int row = ch >> 2, seg = ch & 3;
      int lo = row*40 + seg*8;
      #pragma unroll
      for (int pl = 0; pl < 4; ++pl) *(u16x8*)&sm[pl][lo] = pre[pl][i];
    }
    __syncthreads();

    // ---- issue NEXT tile's global loads (latency hides under MFMA below) ----
    if (kt + 32 < KLEN){
      #pragma unroll
      for (int i = 0; i < 2; ++i){
        int ch = tid*2 + i;
        int row = ch >> 2, seg = ch & 3;
        size_t gk = (size_t)(kBase + kt + 32 + seg*8);
        size_t ga = (size_t)(rowBlk + row)*KD + gk;
        size_t gb = (size_t)(colBlk + row)*KD + gk;
        pre[0][i] = *(const u16x8*)(Ah + ga);
        pre[1][i] = *(const u16x8*)(Al + ga);
        pre[2][i] = *(const u16x8*)(Bh + gb);
        pre[3][i] = *(const u16x8*)(Bl + gb);
      }
    }

    // ---- fragments + 48 MFMA per wave ----
    bf16x8 ah[4], al[4];
    #pragma unroll
    for (int i=0;i<4;++i){
      int r = wr + i*16 + l15;
      ah[i] = *(const bf16x8*)&sm[0][r*40 + g*8];
      al[i] = *(const bf16x8*)&sm[1][r*40 + g*8];
    }
    #pragma unroll
    for (int j=0;j<4;++j){
      int cc = wc + j*16 + l15;
      bf16x8 bh = *(const bf16x8*)&sm[2][cc*40 + g*8];
      bf16x8 bl = *(const bf16x8*)&sm[3][cc*40 + g*8];
      #pragma unroll
      for (int i=0;i<4;++i){
        acc[i][j] = __builtin_amdgcn_mfma_f32_16x16x32_bf16(ah[i], bh, acc[i][j], 0,0,0);
        acc[i][j] = __builtin_amdgcn_mfma_f32_16x16x32_bf16(al[i], bh, acc[i][j], 0,0,0);
        acc[i][j] = __builtin_amdgcn_mfma_f32_16x16x32_bf16(ah[i], bl, acc[i][j], 0,0,0);
      }
    }
    __syncthreads();
  }

  // ---- epilogue.  C element: row = rowBlk+wr+i*16+g*4+r, col = colBlk+wc+j*16+l15 ----
  if (S==3){
    float* Cb = Cf + ((size_t)fb*4 + (size_t)((kBase>>7)))*16384;
    #pragma unroll
    for (int i=0;i<4;++i)
      #pragma unroll
      for (int j=0;j<4;++j)
        #pragma unroll
        for (int r=0;r<4;++r){
          int ro = wr + i*16 + g*4 + r, co = wc + j*16 + l15;
          Cb[ro*128 + co] = acc[i][j][r];
        }
  } else if (S==1){
    u16* Ch = Co + (size_t)fb*2*262144;
    u16* Cl = Ch + 262144;
    const u16* Mh = MqTp + (size_t)b*2*262144;
    const u16* Ml = Mh + 262144;
    #pragma unroll
    for (int i=0;i<4;++i)
      #pragma unroll
      for (int j=0;j<4;++j)
        #pragma unroll
        for (int r=0;r<4;++r){
          int ro = rowBlk + wr + i*16 + g*4 + r, co = colBlk + wc + j*16 + l15;
          size_t o = (size_t)ro*512 + co;
          float a = acc[i][j][r];
          float x = fmaf(a, bf2f(Ml[o]), a * bf2f(Mh[o]));
          u16 hi = f2bf(x);
          Ch[o] = hi;
          Cl[o] = f2bf(x - bf2f(hi));
        }
  } else {
    constexpr int LDC = (S==0) ? 128 : 512;
    u16* Ch = Co + (size_t)fb*2*65536;
    u16* Cl = Ch + 65536;
    #pragma unroll
    for (int i=0;i<4;++i)
      #pragma unroll
      for (int j=0;j<4;++j)
        #pragma unroll
        for (int r=0;r<4;++r){
          int ro = rowBlk + wr + i*16 + g*4 + r, co = colBlk + wc + j*16 + l15;
          float x = acc[i][j][r];
          u16 hi = f2bf(x);
          Ch[(size_t)ro*LDC + co] = hi;
          Cl[(size_t)ro*LDC + co] = f2bf(x - bf2f(hi));
        }
  }
}

// ============ fused: t = 0.5*sum(z2p) + Mp.*v ; nrm ; u ; diff ; v=u ; vT planes ; flag ============
// grid(32), block(1024)
__global__ __launch_bounds__(1024) void k_nf(const float* __restrict__ z2p,
                                             const float* __restrict__ Mp,
                                             float* __restrict__ v,
                                             u16* __restrict__ vTp,
                                             float* __restrict__ diff2,
                                             int* __restrict__ flag,
                                             unsigned* __restrict__ ctr){
  if (*flag == 0) return;
  const int b = blockIdx.x, tid = threadIdx.x;
  const size_t base = (size_t)b*16384;
  __shared__ float sred[1024];
  __shared__ float su[128][129];

  float tv[16], vv[16];
  float n2 = 0.f;
  #pragma unroll
  for (int i = 0; i < 16; ++i){
    int e = tid + i*1024;
    float z = 0.f;
    #pragma unroll
    for (int f = 0; f < 2; ++f)
      #pragma unroll
      for (int cc = 0; cc < 4; ++cc)
        z += z2p[(((size_t)f*BB + b)*4 + cc)*16384 + e];
    vv[i] = v[base + e];
    tv[i] = 0.5f*z + Mp[base + e]*vv[i];
    n2 += tv[i]*tv[i];
  }
  sred[tid] = n2; __syncthreads();
  for (int s = 512; s > 0; s >>= 1){ if (tid < s) sred[tid] += sred[tid+s]; __syncthreads(); }
  float nrm2 = sred[0];
  __syncthreads();

  float rn = (nrm2 == 0.f) ? 0.f : 1.0f / sqrtf(nrm2);
  float d2 = 0.f;
  #pragma unroll
  for (int i = 0; i < 16; ++i){
    int e = tid + i*1024;
    float u = tv[i] * rn;
    float d = u - vv[i];
    d2 += d*d;
    v[base + e] = u;
    su[e>>7][e&127] = u;
  }
  sred[tid] = d2; __syncthreads();
  for (int s = 512; s > 0; s >>= 1){ if (tid < s) sred[tid] += sred[tid+s]; __syncthreads(); }

  // vT planes: vT[p][n] = u[n][p]
  u16* Ch = vTp + (size_t)b*32768;
  u16* Cl = Ch + 16384;
  #pragma unroll
  for (int i = 0; i < 16; ++i){
    int e = tid + i*1024;                  // e = p*128 + n
    float x = su[e & 127][e >> 7];
    u16 hi = f2bf(x);
    Ch[e] = hi;
    Cl[e] = f2bf(x - bf2f(hi));
  }

  if (tid == 0){
    diff2[b] = sred[0];
    __threadfence();
    unsigned old = atomicAdd(ctr, 1u);
    if (old == (unsigned)(BB - 1)){
      __threadfence();
      int any = 0;
      #pragma unroll
      for (int j = 0; j < BB; ++j) any |= (diff2[j] >= EPS2) ? 1 : 0;
      if (!any) *flag = 0;
      *ctr = 0u;
    }
  }
}

extern "C" void kernel_launch(void* const* d_in, const int* in_sizes, int n_in,
                              void* d_out, int out_size, void* d_ws, size_t ws_size,
                              hipStream_t stream) {
  const float* Mp = (const float*)d_in[0];
  const float* Mq = (const float*)d_in[1];
  const float* G1 = (const float*)d_in[2];
  const float* G2 = (const float*)d_in[3];
  const float* H1 = (const float*)d_in[4];
  const float* H2 = (const float*)d_in[5];
  float* v = (float*)d_out;

  u16* Q1T = (u16*)d_ws;                   //  [2][32][2][512][128]
  u16* Q2T = Q1T + 8388608;                //  [2][32][2][512][128]
  u16* P1p = Q2T + 8388608;                //  [2][32][2][128][512]
  u16* P2p = P1p + 8388608;                //  [2][32][2][128][512]
  u16* x1p = P2p + 8388608;                //  [2][32][2][512][128]
  u16* yTp = x1p + 8388608;                //  [2][32][2][512][512]
  u16* z1p = yTp + 33554432;               //  [2][32][2][128][512]
  u16* vTp = z1p + 8388608;                //  [32][2][128][128]
  u16* MqTp = vTp + 1048576;               //  [32][2][512][512]
  float* z2p  = (float*)(MqTp + 16777216); //  [2][32][4][128][128]
  float* diff2 = z2p + 4194304;            //  [32]
  int* flag = (int*)(diff2 + 32);
  unsigned* ctr = (unsigned*)(flag + 1);

  k_initv<<<dim3(512), 256, 0, stream>>>(v, vTp, flag, ctr);
  k_prep <<<dim3(32, 32, 4),  256, 0, stream>>>(G1, H1, G2, H2, P1p, P2p);
  k_prepT<<<dim3(16, 4, 128), 256, 0, stream>>>(H1, G1, H2, G2, Q1T, Q2T);
  k_prepM<<<dim3(16, 16, 32), 256, 0, stream>>>(Mq, MqTp);

  for (int it = 0; it < NITER; ++it) {
    k_gemm<0><<<dim3(256),  256, 0, stream>>>(Q1T, vTp, x1p, nullptr, nullptr, flag);
    k_gemm<1><<<dim3(1024), 256, 0, stream>>>(Q2T, x1p, yTp, nullptr, MqTp,    flag);
    k_gemm<2><<<dim3(256),  256, 0, stream>>>(P1p, yTp, z1p, nullptr, nullptr, flag);
    k_gemm<3><<<dim3(256),  256, 0, stream>>>(z1p, P2p, nullptr, z2p, nullptr, flag);
    k_nf<<<dim3(32), 1024, 0, stream>>>(z2p, Mp, v, vTp, diff2, flag, ctr);
  }
}